// Round 1
// baseline (76.594 us; speedup 1.0000x reference)
//
#include <hip/hip_runtime.h>

#define Bb 16
#define Ll 2048
#define Ee 256
#define E4 64

// workspace layout (floats)
#define XS_OFF 0        // [16][256] sum of valid x rows
#define T_OFF  4096     // [16][256] t = s @ Wk
#define C_OFF  8192     // [16]      c = s . bk
#define W_OFF  8208     // [16]      W = sum_k w
#define U_OFF  8224     // [16][256] u = sum_k w * x_k
#define WS_FLOATS 12320

// Pass 1: Xsum[b,:] = sum_{l < len_b} x[b,l,:]
__global__ void k1_rowsum(const float* __restrict__ x, const int* __restrict__ lengths,
                          float* __restrict__ xs) {
    const int b = blockIdx.y;
    const int len = lengths[b];
    const int rows_per_blk = Ll / gridDim.x;
    const int r0 = blockIdx.x * rows_per_blk;
    if (r0 >= len) return;
    const int r1 = min(r0 + rows_per_blk, len);
    const int tid = threadIdx.x;
    const int q  = tid & 63;   // e-quad index (float4)
    const int rl = tid >> 6;   // row sub-group 0..3
    const float4* xb = (const float4*)(x + (size_t)b * Ll * Ee);
    float4 acc = {0.f, 0.f, 0.f, 0.f};
    for (int r = r0 + rl; r < r1; r += 4) {
        float4 v = xb[(size_t)r * E4 + q];
        acc.x += v.x; acc.y += v.y; acc.z += v.z; acc.w += v.w;
    }
    __shared__ float4 part[256];
    part[tid] = acc;
    __syncthreads();
    if (tid < 64) {
        float4 a = part[tid], b1 = part[64 + tid], c1 = part[128 + tid], d1 = part[192 + tid];
        float* dst = xs + b * Ee + tid * 4;
        atomicAdd(dst + 0, a.x + b1.x + c1.x + d1.x);
        atomicAdd(dst + 1, a.y + b1.y + c1.y + d1.y);
        atomicAdd(dst + 2, a.z + b1.z + c1.z + d1.z);
        atomicAdd(dst + 3, a.w + b1.w + c1.w + d1.w);
    }
}

// s[f] = Xsum . Wq[f,:] + len*bq[f];  t[e] = sum_f s[f]*Wk[f,e];  c = s . bk
__global__ void k2_project(const float* __restrict__ xs, const int* __restrict__ lengths,
                           const float* __restrict__ Wq, const float* __restrict__ bq,
                           const float* __restrict__ Wk, const float* __restrict__ bk,
                           float* __restrict__ T, float* __restrict__ C) {
    const int b = blockIdx.x;
    const int tid = threadIdx.x;
    const float len = (float)lengths[b];
    __shared__ alignas(16) float xs_sh[Ee];
    __shared__ alignas(16) float s_sh[Ee];
    xs_sh[tid] = xs[b * Ee + tid];
    __syncthreads();
    {
        const float4* wrow = (const float4*)(Wq + (size_t)tid * Ee);
        const float4* xv4 = (const float4*)xs_sh;
        float acc = 0.f;
#pragma unroll 8
        for (int j = 0; j < E4; ++j) {
            float4 w = wrow[j]; float4 v = xv4[j];
            acc += w.x * v.x + w.y * v.y + w.z * v.z + w.w * v.w;
        }
        s_sh[tid] = acc + len * bq[tid];
    }
    __syncthreads();
    float acc = 0.f;
#pragma unroll 8
    for (int f = 0; f < Ee; ++f) {
        acc += s_sh[f] * Wk[(size_t)f * Ee + tid];
    }
    T[b * Ee + tid] = acc;
    // c = s . bk  (block reduce)
    float p = s_sh[tid] * bk[tid];
#pragma unroll
    for (int m = 32; m; m >>= 1) p += __shfl_xor(p, m, 64);
    __shared__ float cred[4];
    if ((tid & 63) == 0) cred[tid >> 6] = p;
    __syncthreads();
    if (tid == 0) C[b] = cred[0] + cred[1] + cred[2] + cred[3];
}

// Pass 2: per valid row k:  w = x_k . t + c;  u += w * x_k;  W += w
__global__ void k3_main(const float* __restrict__ x, const int* __restrict__ lengths,
                        const float* __restrict__ T, const float* __restrict__ C,
                        float* __restrict__ U, float* __restrict__ Wsum) {
    const int b = blockIdx.y;
    const int len = lengths[b];
    const int rows_per_blk = Ll / gridDim.x;
    const int r0 = blockIdx.x * rows_per_blk;
    if (r0 >= len) return;
    const int r1 = min(r0 + rows_per_blk, len);
    const int tid = threadIdx.x;
    const int lane = tid & 63;
    const int wid = tid >> 6;
    const float4* xb = (const float4*)(x + (size_t)b * Ll * Ee);
    const float4 tv = ((const float4*)(T + b * Ee))[lane];
    const float cb = C[b];
    float4 uacc = {0.f, 0.f, 0.f, 0.f};
    float wacc = 0.f;
    for (int r = r0 + wid; r < r1; r += 4) {
        float4 xv = xb[(size_t)r * E4 + lane];
        float d = xv.x * tv.x + xv.y * tv.y + xv.z * tv.z + xv.w * tv.w;
#pragma unroll
        for (int m = 32; m; m >>= 1) d += __shfl_xor(d, m, 64);
        float w = d + cb;
        uacc.x += w * xv.x; uacc.y += w * xv.y; uacc.z += w * xv.z; uacc.w += w * xv.w;
        wacc += w;
    }
    float* ub = U + b * Ee + lane * 4;
    atomicAdd(ub + 0, uacc.x);
    atomicAdd(ub + 1, uacc.y);
    atomicAdd(ub + 2, uacc.z);
    atomicAdd(ub + 3, uacc.w);
    if (lane == 0) atomicAdd(Wsum + b, wacc);
}

// out[b,e] = (Wv[e,:] . u[b,:] + bv[e]*W[b]) / L
__global__ void k4_out(const float* __restrict__ U, const float* __restrict__ Wsum,
                       const float* __restrict__ Wv, const float* __restrict__ bv,
                       float* __restrict__ out) {
    const int b = blockIdx.x;
    const int tid = threadIdx.x;
    __shared__ alignas(16) float u_sh[Ee];
    u_sh[tid] = U[b * Ee + tid];
    __syncthreads();
    const float4* wrow = (const float4*)(Wv + (size_t)tid * Ee);
    const float4* u4 = (const float4*)u_sh;
    float acc = 0.f;
#pragma unroll 8
    for (int j = 0; j < E4; ++j) {
        float4 w = wrow[j]; float4 v = u4[j];
        acc += w.x * v.x + w.y * v.y + w.z * v.z + w.w * v.w;
    }
    out[b * Ee + tid] = (acc + bv[tid] * Wsum[b]) * (1.0f / (float)Ll);
}

extern "C" void kernel_launch(void* const* d_in, const int* in_sizes, int n_in,
                              void* d_out, int out_size, void* d_ws, size_t ws_size,
                              hipStream_t stream) {
    const float* x       = (const float*)d_in[0];
    const int*   lengths = (const int*)d_in[1];
    const float* Wq      = (const float*)d_in[2];
    const float* bq      = (const float*)d_in[3];
    const float* Wk      = (const float*)d_in[4];
    const float* bk      = (const float*)d_in[5];
    const float* Wv      = (const float*)d_in[6];
    const float* bv      = (const float*)d_in[7];
    float* out = (float*)d_out;
    float* ws  = (float*)d_ws;

    hipMemsetAsync(d_ws, 0, WS_FLOATS * sizeof(float), stream);
    k1_rowsum<<<dim3(32, Bb), 256, 0, stream>>>(x, lengths, ws + XS_OFF);
    k2_project<<<Bb, 256, 0, stream>>>(ws + XS_OFF, lengths, Wq, bq, Wk, bk,
                                       ws + T_OFF, ws + C_OFF);
    k3_main<<<dim3(64, Bb), 256, 0, stream>>>(x, lengths, ws + T_OFF, ws + C_OFF,
                                              ws + U_OFF, ws + W_OFF);
    k4_out<<<Bb, 256, 0, stream>>>(ws + U_OFF, ws + W_OFF, Wv, bv, out);
}

// Round 2
// 54.566 us; speedup vs baseline: 1.4037x; 1.4037x over previous
//
#include <hip/hip_runtime.h>

#define Bb 16
#define Ll 2048
#define Ee 256
#define E4 64

// workspace layout (floats) — no pre-zeroing required anywhere:
//  P1 slots are written by active k1 blocks and only active slots are read by k2;
//  U/W are zeroed by k2 before k3's atomics.
#define P1_OFF 0                      // [16][16][256] k1 partial row-sums
#define T_OFF  (P1_OFF + Bb*16*Ee)    // [16][256] t = s @ Wk
#define C_OFF  (T_OFF + Bb*Ee)        // [16]      c = s . bk
#define U_OFF  (C_OFF + 16)           // [16][256] u accumulators (zeroed by k2)
#define W_OFF  (U_OFF + Bb*Ee)        // [16]      W accumulators (zeroed by k2)

// Pass 1: per-block partial sums of valid x rows. Block (i,b) covers rows [i*128, i*128+128).
__global__ void k1_rowsum(const float* __restrict__ x, const int* __restrict__ lengths,
                          float* __restrict__ P1) {
    const int b = blockIdx.y;
    const int len = lengths[b];
    const int i = blockIdx.x;
    const int r0 = i * 128;
    if (r0 >= len) return;                    // inactive slot: never read by k2
    const int r1 = min(r0 + 128, len);
    const int tid = threadIdx.x;
    const int lane = tid & 63;
    const int wid = tid >> 6;
    const float4* xb = (const float4*)(x + (size_t)b * Ll * Ee);
    float4 acc = {0.f, 0.f, 0.f, 0.f};
    for (int r = r0 + wid; r < r1; r += 4) {
        float4 v = xb[(size_t)r * E4 + lane];
        acc.x += v.x; acc.y += v.y; acc.z += v.z; acc.w += v.w;
    }
    __shared__ float4 part[256];
    part[tid] = acc;
    __syncthreads();
    if (tid < 64) {
        float4 a = part[tid], b1 = part[64 + tid], c1 = part[128 + tid], d1 = part[192 + tid];
        float4 s = {a.x + b1.x + c1.x + d1.x, a.y + b1.y + c1.y + d1.y,
                    a.z + b1.z + c1.z + d1.z, a.w + b1.w + c1.w + d1.w};
        ((float4*)(P1 + ((size_t)(b * 16 + i)) * Ee))[tid] = s;
    }
}

// Reduce P1 -> Xsum; s = Xsum@Wq^T + len*bq; t = s@Wk; c = s.bk. Also zero U/W for k3.
__global__ void k2_project(const float* __restrict__ P1, const int* __restrict__ lengths,
                           const float* __restrict__ Wq, const float* __restrict__ bq,
                           const float* __restrict__ Wk, const float* __restrict__ bk,
                           float* __restrict__ T, float* __restrict__ C,
                           float* __restrict__ U, float* __restrict__ Wz) {
    const int b = blockIdx.x;
    const int tid = threadIdx.x;
    const int len = lengths[b];
    const int nblk = (len + 127) >> 7;
    // zero the k3 accumulators (runs before k3 in stream order)
    U[b * Ee + tid] = 0.f;
    if (tid == 0) Wz[b] = 0.f;
    __shared__ alignas(16) float xs_sh[Ee];
    __shared__ alignas(16) float s_sh[Ee];
    {
        float a = 0.f;
        for (int i = 0; i < nblk; ++i) a += P1[((size_t)(b * 16 + i)) * Ee + tid];
        xs_sh[tid] = a;
    }
    __syncthreads();
    {
        const float4* wrow = (const float4*)(Wq + (size_t)tid * Ee);
        const float4* xv4 = (const float4*)xs_sh;
        float acc = 0.f;
#pragma unroll 8
        for (int j = 0; j < E4; ++j) {
            float4 w = wrow[j]; float4 v = xv4[j];
            acc += w.x * v.x + w.y * v.y + w.z * v.z + w.w * v.w;
        }
        s_sh[tid] = acc + (float)len * bq[tid];
    }
    __syncthreads();
    float acc = 0.f;
#pragma unroll 8
    for (int f = 0; f < Ee; ++f) acc += s_sh[f] * Wk[(size_t)f * Ee + tid];
    T[b * Ee + tid] = acc;
    float p = s_sh[tid] * bk[tid];
#pragma unroll
    for (int m = 32; m; m >>= 1) p += __shfl_xor(p, m, 64);
    __shared__ float cred[4];
    if ((tid & 63) == 0) cred[tid >> 6] = p;
    __syncthreads();
    if (tid == 0) C[b] = cred[0] + cred[1] + cred[2] + cred[3];
}

// Pass 2: per valid row k: w = x_k.t + c; u += w*x_k; W += w. Block covers 64 rows.
__global__ void k3_main(const float* __restrict__ x, const int* __restrict__ lengths,
                        const float* __restrict__ T, const float* __restrict__ C,
                        float* __restrict__ U, float* __restrict__ Wsum) {
    const int b = blockIdx.y;
    const int len = lengths[b];
    const int r0 = blockIdx.x * 64;
    if (r0 >= len) return;
    const int r1 = min(r0 + 64, len);
    const int tid = threadIdx.x;
    const int lane = tid & 63;
    const int wid = tid >> 6;
    const float4* xb = (const float4*)(x + (size_t)b * Ll * Ee);
    const float4 tv = ((const float4*)(T + b * Ee))[lane];
    const float cb = C[b];
    float4 uacc = {0.f, 0.f, 0.f, 0.f};
    float wacc = 0.f;
    for (int r = r0 + wid; r < r1; r += 4) {
        float4 xv = xb[(size_t)r * E4 + lane];
        float d = xv.x * tv.x + xv.y * tv.y + xv.z * tv.z + xv.w * tv.w;
#pragma unroll
        for (int m = 32; m; m >>= 1) d += __shfl_xor(d, m, 64);
        float w = d + cb;
        uacc.x += w * xv.x; uacc.y += w * xv.y; uacc.z += w * xv.z; uacc.w += w * xv.w;
        wacc += w;
    }
    __shared__ float4 part[256];
    __shared__ float cw[4];
    part[tid] = uacc;
    if (lane == 0) cw[wid] = wacc;   // wacc is wave-uniform (w uniform after full-wave reduce)
    __syncthreads();
    if (tid < 64) {
        float4 a = part[tid], b1 = part[64 + tid], c1 = part[128 + tid], d1 = part[192 + tid];
        float* ub = U + b * Ee + tid * 4;
        atomicAdd(ub + 0, a.x + b1.x + c1.x + d1.x);
        atomicAdd(ub + 1, a.y + b1.y + c1.y + d1.y);
        atomicAdd(ub + 2, a.z + b1.z + c1.z + d1.z);
        atomicAdd(ub + 3, a.w + b1.w + c1.w + d1.w);
    }
    if (tid == 0) atomicAdd(Wsum + b, cw[0] + cw[1] + cw[2] + cw[3]);
}

// out[b,e] = (Wv[e,:].u[b,:] + bv[e]*W[b]) / L
__global__ void k4_out(const float* __restrict__ U, const float* __restrict__ Wsum,
                       const float* __restrict__ Wv, const float* __restrict__ bv,
                       float* __restrict__ out) {
    const int b = blockIdx.x;
    const int tid = threadIdx.x;
    __shared__ alignas(16) float u_sh[Ee];
    u_sh[tid] = U[b * Ee + tid];
    __syncthreads();
    const float4* wrow = (const float4*)(Wv + (size_t)tid * Ee);
    const float4* u4 = (const float4*)u_sh;
    float acc = 0.f;
#pragma unroll 8
    for (int j = 0; j < E4; ++j) {
        float4 w = wrow[j]; float4 v = u4[j];
        acc += w.x * v.x + w.y * v.y + w.z * v.z + w.w * v.w;
    }
    out[b * Ee + tid] = (acc + bv[tid] * Wsum[b]) * (1.0f / (float)Ll);
}

extern "C" void kernel_launch(void* const* d_in, const int* in_sizes, int n_in,
                              void* d_out, int out_size, void* d_ws, size_t ws_size,
                              hipStream_t stream) {
    const float* x       = (const float*)d_in[0];
    const int*   lengths = (const int*)d_in[1];
    const float* Wq      = (const float*)d_in[2];
    const float* bq      = (const float*)d_in[3];
    const float* Wk      = (const float*)d_in[4];
    const float* bk      = (const float*)d_in[5];
    const float* Wv      = (const float*)d_in[6];
    const float* bv      = (const float*)d_in[7];
    float* out = (float*)d_out;
    float* ws  = (float*)d_ws;

    k1_rowsum<<<dim3(16, Bb), 256, 0, stream>>>(x, lengths, ws + P1_OFF);
    k2_project<<<Bb, 256, 0, stream>>>(ws + P1_OFF, lengths, Wq, bq, Wk, bk,
                                       ws + T_OFF, ws + C_OFF, ws + U_OFF, ws + W_OFF);
    k3_main<<<dim3(32, Bb), 256, 0, stream>>>(x, lengths, ws + T_OFF, ws + C_OFF,
                                              ws + U_OFF, ws + W_OFF);
    k4_out<<<Bb, 256, 0, stream>>>(ws + U_OFF, ws + W_OFF, Wv, bv, out);
}